// Round 1
// baseline (558.768 us; speedup 1.0000x reference)
//
#include <hip/hip_runtime.h>

typedef __bf16 bf16;
typedef __bf16 bf16x8 __attribute__((ext_vector_type(8)));
typedef __bf16 bf16x4 __attribute__((ext_vector_type(4)));
typedef float  f32x4  __attribute__((ext_vector_type(4)));

// Problem constants: FX=64, FU=64, f_in=192, H=256, FE_OUT=64
#define KDIM 192
#define HDIM 256
#define NOUT 64

// ---------------------------------------------------------------------------
// Prep: W1 [192][256] fp32 -> W1T [256][192] bf16 ; W2 [256][64] -> W2T [64][256]
// ---------------------------------------------------------------------------
__global__ __launch_bounds__(256) void prep_weights(
    const float* __restrict__ W1, const float* __restrict__ W2,
    bf16* __restrict__ W1T, bf16* __restrict__ W2T)
{
    int gid = blockIdx.x * 256 + threadIdx.x;
    if (gid < KDIM * HDIM) {                  // 49152 = W1T elements
        int n = gid / KDIM;                   // 0..255
        int k = gid - n * KDIM;               // 0..191
        W1T[gid] = (bf16)W1[k * HDIM + n];
    } else {
        int g2 = gid - KDIM * HDIM;           // 0..16383
        int n = g2 >> 8;                      // 0..63
        int k = g2 & 255;                     // 0..255
        W2T[g2] = (bf16)W2[k * NOUT + n];
    }
}

// ---------------------------------------------------------------------------
// Fused edge MLP over 64-edge tiles (grid-stride, persistent blocks).
// Changes vs prior version:
//  * next-tile prefetch issued AFTER barrier A -> its vmcnt drain happens at
//    barrier B, ~one full layer-1 later (HBM latency hidden, no cold stall)
//  * epilogue 2 goes through a wave-private LDS transpose (outs overlays xs,
//    band-aligned: row stride 400B matches xs, so wave w's outs rows 16w..16w+15
//    are exactly the rows wave w itself stages/reads -> no barrier needed),
//    then full-128B-line f32x4 nontemporal stores (kills 2x write amplification
//    + RMW fetch)
//  * src/dest loads nontemporal (no reuse) so u + weights stay L2-resident
// ---------------------------------------------------------------------------
__global__ __launch_bounds__(256, 2) void edge_mlp(
    const float* __restrict__ srcf, const float* __restrict__ destf,
    const float* __restrict__ u,    const int* __restrict__ batch,
    const bf16* __restrict__ W1T,   const float* __restrict__ b1,
    const bf16* __restrict__ W2T,   const float* __restrict__ b2,
    float* __restrict__ out, int E)
{
    __shared__ __align__(16) unsigned char smem[64 * 200 * 2 + 64 * 264 * 2];
    bf16  (*xs)[200]   = (bf16 (*)[200])smem;                    // 25600 B
    bf16  (*hs)[264]   = (bf16 (*)[264])(smem + 64 * 200 * 2);   // 33792 B
    float (*outs)[100] = (float (*)[100])smem;  // overlays xs, band-aligned

    const int tid  = threadIdx.x;
    const int row  = tid >> 2;        // 0..63  (staging row)
    const int c0   = (tid & 3) * 16;  // 0..48  (staging col base)
    const int wave = tid >> 6;
    const int lane = tid & 63;
    const int q    = lane >> 4;       // quad 0..3
    const int cl   = lane & 15;       // 0..15

    const int ntiles = (E + 63) >> 6;
    const int stride = gridDim.x;

    int it = blockIdx.x;
    if (it >= ntiles) return;

    const int wn0 = wave * 64;
    const int m0  = wave * 16;

    // loop-invariant biases (hoisted)
    float bias1[4], bias2[4];
#pragma unroll
    for (int nt = 0; nt < 4; ++nt) {
        bias1[nt] = b1[wn0 + nt * 16 + cl];
        bias2[nt] = b2[nt * 16 + cl];
    }

    f32x4 dr[4], sr[4], ur[4];

    // ---- preamble: tile(it) -> regs ; batch row for tile(it+stride) ----
    {
        int e = it * 64 + row;
        if (e < E) {
            int b = batch[e];
            const f32x4* dp = (const f32x4*)(destf + (size_t)e * 64 + c0);
            const f32x4* sp = (const f32x4*)(srcf  + (size_t)e * 64 + c0);
            const f32x4* up = (const f32x4*)(u     + (size_t)b * 64 + c0);
#pragma unroll
            for (int i = 0; i < 4; ++i) {
                dr[i] = __builtin_nontemporal_load(dp + i);
                sr[i] = __builtin_nontemporal_load(sp + i);
                ur[i] = up[i];
            }
        } else {
#pragma unroll
            for (int i = 0; i < 4; ++i) {
                dr[i] = f32x4{0.f, 0.f, 0.f, 0.f};
                sr[i] = dr[i]; ur[i] = dr[i];
            }
        }
    }
    int itn = it + stride;
    int bn  = 0;
    if (itn < ntiles) {
        int en = itn * 64 + row;
        if (en < E) bn = batch[en];
    }

    while (true) {
        const int e0 = it * 64;

        // ---- stage xs from regs (wave-private row band 16w..16w+15) ----
#pragma unroll
        for (int i = 0; i < 4; ++i) {
            bf16x4 db = { (bf16)dr[i].x, (bf16)dr[i].y, (bf16)dr[i].z, (bf16)dr[i].w };
            bf16x4 sb = { (bf16)sr[i].x, (bf16)sr[i].y, (bf16)sr[i].z, (bf16)sr[i].w };
            bf16x4 ub = { (bf16)ur[i].x, (bf16)ur[i].y, (bf16)ur[i].z, (bf16)ur[i].w };
            *(bf16x4*)&xs[row][c0 + i * 4]       = db;
            *(bf16x4*)&xs[row][64 + c0 + i * 4]  = sb;
            *(bf16x4*)&xs[row][128 + c0 + i * 4] = ub;
        }

        __syncthreads();   // A: xs ready (only drains last tile's stores, cheap)

        // ---- prefetch next tile AFTER barrier A: the forced vmcnt(0) drain
        //      lands at barrier B, one full layer-1 later -> latency covered ----
        const bool hasnext = (itn < ntiles);
        f32x4 dr2[4], sr2[4], ur2[4];
        if (hasnext) {
            int en = itn * 64 + row;
            if (en < E) {
                const f32x4* dp = (const f32x4*)(destf + (size_t)en * 64 + c0);
                const f32x4* sp = (const f32x4*)(srcf  + (size_t)en * 64 + c0);
                const f32x4* up = (const f32x4*)(u     + (size_t)bn * 64 + c0);
#pragma unroll
                for (int i = 0; i < 4; ++i) {
                    dr2[i] = __builtin_nontemporal_load(dp + i);
                    sr2[i] = __builtin_nontemporal_load(sp + i);
                    ur2[i] = up[i];
                }
            } else {
#pragma unroll
                for (int i = 0; i < 4; ++i) {
                    dr2[i] = f32x4{0.f, 0.f, 0.f, 0.f};
                    sr2[i] = dr2[i]; ur2[i] = dr2[i];
                }
            }
        }
        int itnn = itn + stride;
        int bnn  = 0;
        if (itnn < ntiles) {
            int enn = itnn * 64 + row;
            if (enn < E) bnn = batch[enn];
        }

        // ---- layer 1: wave owns N cols [64w, 64w+64), all 64 M rows ----
        f32x4 acc[4][4] = {};
        const bf16* w1base = W1T + (size_t)wn0 * KDIM;
#pragma unroll
        for (int ks = 0; ks < 6; ++ks) {
            const int k0 = ks * 32 + q * 8;
            bf16x8 a[4], bb[4];
#pragma unroll
            for (int mt = 0; mt < 4; ++mt)
                a[mt] = *(const bf16x8*)&xs[mt * 16 + cl][k0];
#pragma unroll
            for (int nt = 0; nt < 4; ++nt)
                bb[nt] = *(const bf16x8*)(w1base + (size_t)(nt * 16 + cl) * KDIM + k0);
#pragma unroll
            for (int mt = 0; mt < 4; ++mt)
#pragma unroll
                for (int nt = 0; nt < 4; ++nt)
                    acc[mt][nt] = __builtin_amdgcn_mfma_f32_16x16x32_bf16(
                        a[mt], bb[nt], acc[mt][nt], 0, 0, 0);
        }

        // ---- epilogue 1: +b1, relu, bf16 -> hs ----
#pragma unroll
        for (int nt = 0; nt < 4; ++nt) {
#pragma unroll
            for (int mt = 0; mt < 4; ++mt) {
#pragma unroll
                for (int r = 0; r < 4; ++r) {
                    float v = acc[mt][nt][r] + bias1[nt];
                    v = v > 0.f ? v : 0.f;
                    hs[mt * 16 + q * 4 + r][wn0 + nt * 16 + cl] = (bf16)v;
                }
            }
        }
        __syncthreads();   // B: hs ready (drains prefetch, covered by layer 1)

        // ---- layer 2: wave owns M rows [16w, 16w+16), K=256 ----
        f32x4 acc2[4] = {};
#pragma unroll
        for (int ks = 0; ks < 8; ++ks) {
            const int k0 = ks * 32 + q * 8;
            bf16x8 a = *(const bf16x8*)&hs[m0 + cl][k0];
#pragma unroll
            for (int nt = 0; nt < 4; ++nt) {
                bf16x8 bb = *(const bf16x8*)(W2T + (size_t)(nt * 16 + cl) * HDIM + k0);
                acc2[nt] = __builtin_amdgcn_mfma_f32_16x16x32_bf16(a, bb, acc2[nt], 0, 0, 0);
            }
        }

        // ---- epilogue 2: +b2 -> wave-private LDS band (outs overlays xs;
        //      stride 400B == xs stride, so band w == wave w's own rows;
        //      all other waves' xs reads finished before barrier B) ----
#pragma unroll
        for (int nt = 0; nt < 4; ++nt)
#pragma unroll
            for (int r = 0; r < 4; ++r)
                outs[m0 + q * 4 + r][nt * 16 + cl] = acc2[nt][r] + bias2[nt];

        // same-wave ds_write -> ds_read (in-order, compiler inserts lgkmcnt);
        // each store instruction now covers 1 KB contiguous = full HBM lines
#pragma unroll
        for (int p = 0; p < 4; ++p) {
            const int orow = m0 + p * 4 + q;
            const int ee   = e0 + orow;
            if (ee < E) {
                f32x4 v = *(const f32x4*)&outs[orow][cl * 4];
                __builtin_nontemporal_store(v, (f32x4*)(out + (size_t)ee * 64 + cl * 4));
            }
        }

        if (!hasnext) break;
        it = itn; itn = itnn; bn = bnn;
#pragma unroll
        for (int i = 0; i < 4; ++i) { dr[i] = dr2[i]; sr[i] = sr2[i]; ur[i] = ur2[i]; }
    }
}

extern "C" void kernel_launch(void* const* d_in, const int* in_sizes, int n_in,
                              void* d_out, int out_size, void* d_ws, size_t ws_size,
                              hipStream_t stream)
{
    const float* srcf  = (const float*)d_in[0];
    const float* destf = (const float*)d_in[1];
    // d_in[2] = edge_attr: UNUSED by reference — never touched.
    const float* u     = (const float*)d_in[3];
    const int*   batch = (const int*)d_in[4];
    const float* W1    = (const float*)d_in[5];
    const float* b1    = (const float*)d_in[6];
    const float* W2    = (const float*)d_in[7];
    const float* b2    = (const float*)d_in[8];
    float* out = (float*)d_out;

    const int E = in_sizes[0] / 64;   // src is [E, 64]

    bf16* W1T = (bf16*)d_ws;                  // 256*192 bf16 = 98304 B
    bf16* W2T = W1T + KDIM * HDIM;            // 64*256  bf16 = 32768 B

    prep_weights<<<(KDIM * HDIM + HDIM * NOUT) / 256, 256, 0, stream>>>(W1, W2, W1T, W2T);

    const int ntiles = (E + 63) / 64;
    const int nblocks = ntiles < 512 ? ntiles : 512;   // one persistent generation
    edge_mlp<<<nblocks, 256, 0, stream>>>(srcf, destf, u, batch,
                                          W1T, b1, W2T, b2, out, E);
}

// Round 2
// 556.795 us; speedup vs baseline: 1.0035x; 1.0035x over previous
//
#include <hip/hip_runtime.h>

typedef __bf16 bf16;
typedef __bf16 bf16x8 __attribute__((ext_vector_type(8)));
typedef __bf16 bf16x4 __attribute__((ext_vector_type(4)));
typedef float  f32x4  __attribute__((ext_vector_type(4)));

// Problem constants: FX=64, FU=64, f_in=192, H=256, FE_OUT=64
#define KDIM 192
#define HDIM 256
#define NOUT 64

// ---------------------------------------------------------------------------
// Prep: W1 [192][256] fp32 -> W1T [256][192] bf16 ; W2 [256][64] -> W2T [64][256]
// ---------------------------------------------------------------------------
__global__ __launch_bounds__(256) void prep_weights(
    const float* __restrict__ W1, const float* __restrict__ W2,
    bf16* __restrict__ W1T, bf16* __restrict__ W2T)
{
    int gid = blockIdx.x * 256 + threadIdx.x;
    if (gid < KDIM * HDIM) {                  // 49152 = W1T elements
        int n = gid / KDIM;                   // 0..255
        int k = gid - n * KDIM;               // 0..191
        W1T[gid] = (bf16)W1[k * HDIM + n];
    } else {
        int g2 = gid - KDIM * HDIM;           // 0..16383
        int n = g2 >> 8;                      // 0..63
        int k = g2 & 255;                     // 0..255
        W2T[g2] = (bf16)W2[k * NOUT + n];
    }
}

// ---------------------------------------------------------------------------
// Fused edge MLP over 64-edge tiles (grid-stride, persistent blocks).
// Round-2 changes (each justified by round-1 counters):
//  * FLAT-REMAP staging loads: thread t reads float4 #(j*256+t) of the tile ->
//    every wave instruction covers 4KB contiguous; kills the 16-rows-sparse
//    pattern whose 3/4 line re-use thrashed L1/L2 (FETCH was 2.4x ideal).
//  * staging loads for tile t+1 are issued AFTER the last W2T load of layer 2:
//    vmcnt completes IN-ORDER, so weight-load waits must never queue behind
//    outstanding HBM staging loads (round-1's regression). Drain of staging
//    happens at next loop-top convert, covered by epilogue2 + barrier A.
//  * out stores: plain (not nontemporal) f32x4 -> full-line L2 write-combine
//    (nt stores left 1.53x write amplification).
//  * outs overlays HS (row stride 528B, wave-private band both sides; epi-1
//    hs overwrite is fenced by barrier A, layer-2 reads are same-wave band).
// ---------------------------------------------------------------------------
__global__ __launch_bounds__(256, 2) void edge_mlp(
    const float* __restrict__ srcf, const float* __restrict__ destf,
    const float* __restrict__ u,    const int* __restrict__ batch,
    const bf16* __restrict__ W1T,   const float* __restrict__ b1,
    const bf16* __restrict__ W2T,   const float* __restrict__ b2,
    float* __restrict__ out, int E)
{
    __shared__ __align__(16) unsigned char smem[64 * 200 * 2 + 64 * 264 * 2];
    bf16  (*xs)[200]   = (bf16 (*)[200])smem;                    // 25600 B
    bf16  (*hs)[264]   = (bf16 (*)[264])(smem + 64 * 200 * 2);   // 33792 B
    float (*outs)[132] = (float (*)[132])(smem + 64 * 200 * 2);  // overlays hs
                                                                 // (528B rows)

    const int tid  = threadIdx.x;
    const int row  = tid >> 2;        // 0..63  (u-staging row)
    const int c0   = (tid & 3) * 16;  // 0..48  (u-staging col base)
    const int wave = tid >> 6;
    const int lane = tid & 63;
    const int q    = lane >> 4;       // quad 0..3
    const int cl   = lane & 15;       // 0..15

    // flat-remap staging coords: float4 #(j*256+tid) of the 64x64 f32 tile
    const int r0 = tid >> 4;          // row for j=0; j adds 16
    const int cp = tid & 15;          // float4 slot within row (16 per row)

    const int ntiles = (E + 63) >> 6;
    const int stride = gridDim.x;

    int it = blockIdx.x;
    if (it >= ntiles) return;

    const int wn0 = wave * 64;
    const int m0  = wave * 16;

    // loop-invariant biases
    float bias1[4], bias2[4];
#pragma unroll
    for (int nt = 0; nt < 4; ++nt) {
        bias1[nt] = b1[wn0 + nt * 16 + cl];
        bias2[nt] = b2[nt * 16 + cl];
    }

    f32x4 dr[4], sr[4], ur[4];
    const f32x4 zero4 = {0.f, 0.f, 0.f, 0.f};

    // ---- preamble: tile(it) -> regs ----
    {
        const size_t tb = (size_t)it * 1024;   // tile base in float4 units
#pragma unroll
        for (int j = 0; j < 4; ++j) {
            const int g = j * 256 + tid;
            const int e = it * 64 + (g >> 4);
            if (e < E) {
                dr[j] = __builtin_nontemporal_load((const f32x4*)destf + tb + g);
                sr[j] = __builtin_nontemporal_load((const f32x4*)srcf  + tb + g);
            } else { dr[j] = zero4; sr[j] = zero4; }
        }
        const int e = it * 64 + row;
        if (e < E) {
            const int b = batch[e];
            const f32x4* up = (const f32x4*)(u + (size_t)b * 64 + c0);
#pragma unroll
            for (int i = 0; i < 4; ++i) ur[i] = up[i];
        } else {
#pragma unroll
            for (int i = 0; i < 4; ++i) ur[i] = zero4;
        }
    }
    int itn = it + stride;
    int bn  = 0;
    if (itn < ntiles) {
        int en = itn * 64 + row;
        if (en < E) bn = batch[en];
    }

    while (true) {
        const int e0 = it * 64;

        // ---- stage xs from regs (convert fp32 -> bf16) ----
#pragma unroll
        for (int j = 0; j < 4; ++j) {
            const int r = j * 16 + r0;
            bf16x4 db = { (bf16)dr[j].x, (bf16)dr[j].y, (bf16)dr[j].z, (bf16)dr[j].w };
            bf16x4 sb = { (bf16)sr[j].x, (bf16)sr[j].y, (bf16)sr[j].z, (bf16)sr[j].w };
            *(bf16x4*)&xs[r][cp * 4]      = db;
            *(bf16x4*)&xs[r][64 + cp * 4] = sb;
        }
#pragma unroll
        for (int i = 0; i < 4; ++i) {
            bf16x4 ub = { (bf16)ur[i].x, (bf16)ur[i].y, (bf16)ur[i].z, (bf16)ur[i].w };
            *(bf16x4*)&xs[row][128 + c0 + i * 4] = ub;
        }

        __syncthreads();   // A: xs ready (staging loads already drained at convert)

        // ---- layer 1: wave owns N cols [64w, 64w+64), all 64 M rows ----
        // vmem stream here is W1T only (L2-resident) — no HBM loads queued ahead
        f32x4 acc[4][4] = {};
        const bf16* w1base = W1T + (size_t)wn0 * KDIM;
#pragma unroll
        for (int ks = 0; ks < 6; ++ks) {
            const int k0 = ks * 32 + q * 8;
            bf16x8 a[4], bb[4];
#pragma unroll
            for (int mt = 0; mt < 4; ++mt)
                a[mt] = *(const bf16x8*)&xs[mt * 16 + cl][k0];
#pragma unroll
            for (int nt = 0; nt < 4; ++nt)
                bb[nt] = *(const bf16x8*)(w1base + (size_t)(nt * 16 + cl) * KDIM + k0);
#pragma unroll
            for (int mt = 0; mt < 4; ++mt)
#pragma unroll
                for (int nt = 0; nt < 4; ++nt)
                    acc[mt][nt] = __builtin_amdgcn_mfma_f32_16x16x32_bf16(
                        a[mt], bb[nt], acc[mt][nt], 0, 0, 0);
        }

        // ---- epilogue 1: +b1, relu, bf16 -> hs ----
#pragma unroll
        for (int nt = 0; nt < 4; ++nt) {
#pragma unroll
            for (int mt = 0; mt < 4; ++mt) {
#pragma unroll
                for (int r = 0; r < 4; ++r) {
                    float v = acc[mt][nt][r] + bias1[nt];
                    v = v > 0.f ? v : 0.f;
                    hs[mt * 16 + q * 4 + r][wn0 + nt * 16 + cl] = (bf16)v;
                }
            }
        }
        __syncthreads();   // B: hs ready

        // ---- layer 2: wave owns M rows [16w, 16w+16), K=256 ----
        f32x4 acc2[4] = {};
#pragma unroll
        for (int ks = 0; ks < 8; ++ks) {
            const int k0 = ks * 32 + q * 8;
            bf16x8 a = *(const bf16x8*)&hs[m0 + cl][k0];
#pragma unroll
            for (int nt = 0; nt < 4; ++nt) {
                bf16x8 bb = *(const bf16x8*)(W2T + (size_t)(nt * 16 + cl) * HDIM + k0);
                acc2[nt] = __builtin_amdgcn_mfma_f32_16x16x32_bf16(a, bb, acc2[nt], 0, 0, 0);
            }
        }

        // ---- staging loads for tile t+1: issued AFTER all weight loads so
        //      no weight wait queues behind them (in-order vmcnt); drained at
        //      next loop-top convert, covered by epilogue2 + barrier A ----
        const bool hasnext = (itn < ntiles);
        f32x4 dr2[4], sr2[4], ur2[4];
        if (hasnext) {
            const size_t tb = (size_t)itn * 1024;
#pragma unroll
            for (int j = 0; j < 4; ++j) {
                const int g = j * 256 + tid;
                const int en = itn * 64 + (g >> 4);
                if (en < E) {
                    dr2[j] = __builtin_nontemporal_load((const f32x4*)destf + tb + g);
                    sr2[j] = __builtin_nontemporal_load((const f32x4*)srcf  + tb + g);
                } else { dr2[j] = zero4; sr2[j] = zero4; }
            }
            const int en = itn * 64 + row;
            if (en < E) {
                const f32x4* up = (const f32x4*)(u + (size_t)bn * 64 + c0);
#pragma unroll
                for (int i = 0; i < 4; ++i) ur2[i] = up[i];
            } else {
#pragma unroll
                for (int i = 0; i < 4; ++i) ur2[i] = zero4;
            }
        }
        int itnn = itn + stride;
        int bnn  = 0;
        if (itnn < ntiles) {
            int enn = itnn * 64 + row;
            if (enn < E) bnn = batch[enn];
        }

        // ---- epilogue 2: +b2 -> outs (overlays hs, wave-private band:
        //      layer-2 read hs rows [m0,m0+16) same wave, program-ordered) ----
#pragma unroll
        for (int nt = 0; nt < 4; ++nt)
#pragma unroll
            for (int r = 0; r < 4; ++r)
                outs[m0 + q * 4 + r][nt * 16 + cl] = acc2[nt][r] + bias2[nt];

        // full-line stores: 4 consecutive 256B rows = 1KB contiguous per instr
#pragma unroll
        for (int p = 0; p < 4; ++p) {
            const int orow = m0 + p * 4 + q;
            const int ee   = e0 + orow;
            if (ee < E) {
                f32x4 v = *(const f32x4*)&outs[orow][cl * 4];
                *(f32x4*)(out + (size_t)ee * 64 + cl * 4) = v;   // plain store
            }
        }

        if (!hasnext) break;
        it = itn; itn = itnn; bn = bnn;
#pragma unroll
        for (int i = 0; i < 4; ++i) { dr[i] = dr2[i]; sr[i] = sr2[i]; ur[i] = ur2[i]; }
    }
}

extern "C" void kernel_launch(void* const* d_in, const int* in_sizes, int n_in,
                              void* d_out, int out_size, void* d_ws, size_t ws_size,
                              hipStream_t stream)
{
    const float* srcf  = (const float*)d_in[0];
    const float* destf = (const float*)d_in[1];
    // d_in[2] = edge_attr: UNUSED by reference — never touched.
    const float* u     = (const float*)d_in[3];
    const int*   batch = (const int*)d_in[4];
    const float* W1    = (const float*)d_in[5];
    const float* b1    = (const float*)d_in[6];
    const float* W2    = (const float*)d_in[7];
    const float* b2    = (const float*)d_in[8];
    float* out = (float*)d_out;

    const int E = in_sizes[0] / 64;   // src is [E, 64]

    bf16* W1T = (bf16*)d_ws;                  // 256*192 bf16 = 98304 B
    bf16* W2T = W1T + KDIM * HDIM;            // 64*256  bf16 = 32768 B

    prep_weights<<<(KDIM * HDIM + HDIM * NOUT) / 256, 256, 0, stream>>>(W1, W2, W1T, W2T);

    const int ntiles = (E + 63) / 64;
    const int nblocks = ntiles < 512 ? ntiles : 512;   // 2 blocks/CU resident
    edge_mlp<<<nblocks, 256, 0, stream>>>(srcf, destf, u, batch,
                                          W1T, b1, W2T, b2, out, E);
}